// Round 5
// baseline (952.297 us; speedup 1.0000x reference)
//
#include <hip/hip_runtime.h>
#include <math.h>

// ---------------------------------------------------------------------------
// Problem constants: B=1024, XDIM=62, TWIN=10, INCH=128, MID=256, OUT=512,
// K=3, K1=10, LIN=512.  REGIONS partition nodes 0..61 exactly once.
// hc_b1/hc_b2 dropped: BN subtracts the batch mean -> bias-invariant.
// ---------------------------------------------------------------------------

// concat order of nodes (p -> node)
__constant__ int cOrder[62] = {
  0,1,2,3,4,
  5,6,7,14,15,16,
  8,9,10,17,18,19,
  11,12,13,20,21,22,
  23,24,25,32,33,34,
  26,27,28,35,36,37,
  29,30,31,38,39,40,
  41,42,43,50,51,57,
  44,45,46,52,53,54,58,59,60,
  47,48,49,55,56,61
};
// node -> position in concat order
__constant__ int cPos[62] = {
  0,1,2,3,4, 5,6,7, 11,12,13, 17,18,19, 8,9,10, 14,15,16, 20,21,22,
  23,24,25, 29,30,31, 35,36,37, 26,27,28, 32,33,34, 38,39,40,
  41,42,43, 47,48,49, 56,57,58, 44,45, 50,51,52, 59,60, 46, 53,54,55, 61
};
// per-region K (=L*128) and cumulative k offset
__constant__ int cRegK[10]   = {640,768,768,768,768,768,768,768,1152,768};
__constant__ int cRegCum[10] = {0,640,1408,2176,2944,3712,4480,5248,6016,7168};

struct Ptr10 { const float* p[10]; };

typedef __attribute__((ext_vector_type(8))) short bf16x8;
typedef __attribute__((ext_vector_type(4))) float f32x4;

__device__ __forceinline__ float gelu_exact(float v){
  return 0.5f * v * (1.0f + erff(v * 0.70710678118654752f));
}
__device__ __forceinline__ unsigned short f2bf(float f){
  unsigned u = __float_as_uint(f);
  unsigned r = (u + 0x7fffu + ((u >> 16) & 1u)) >> 16;
  return (unsigned short)r;
}
__device__ __forceinline__ float bf2f(unsigned short u){
  return __uint_as_float(((unsigned)u) << 16);
}
__device__ __forceinline__ void load_lds16(const unsigned short* g, unsigned short* l){
  __builtin_amdgcn_global_load_lds(
      (const __attribute__((address_space(1))) void*)g,
      (__attribute__((address_space(3))) void*)l, 16, 0, 0);
}

// ---------------------------------------------------------------------------
// MFMA GEMM: C(MxN) = A(MxK) @ BT(NxK)^T, bf16 in, fp32 acc. 128x128 tile,
// BK=32, XOR-swizzled LDS, global_load_lds w=16.
// mcCount>0: 1-D grid with XCD-cluster swizzle. Blocks with ids
// {k, k+8, .., k+56} form a 2m x 4n cluster sharing one XCD (id%8) and
// adjacent dispatch slots -> A-pair + B-quad stay L2-resident (~3.6MB < 4MB).
// Requires nTiles==4 and gridDim.x == mcCount*zCount*8, mTiles = 2*mcCount.
// mcCount==0: plain 3-D grid (blockIdx.{x,y,z} = m,n,z tiles).
// RELU=true: bf16+relu store. RELU=false: fp32 split-K partial store.
// ---------------------------------------------------------------------------
template<bool RELU>
__global__ __launch_bounds__(256) void k_mfma(
    const unsigned short* __restrict__ A, long lda,
    const unsigned short* __restrict__ BT, long ldb,
    void* __restrict__ Cv, int ldc, int kPerZ, long cStrideZ, int mcCount){
  __shared__ unsigned short As[128*32];
  __shared__ unsigned short Bs[128*32];
  int mt, nt, zt;
  if (mcCount){
    int id = blockIdx.x;
    int c = ((id >> 6) << 3) + (id & 7);   // cluster index
    int member = (id >> 3) & 7;
    zt = c / mcCount;
    int mc = c - zt*mcCount;
    mt = mc*2 + (member >> 2);
    nt = member & 3;
  } else { mt = blockIdx.x; nt = blockIdx.y; zt = blockIdx.z; }
  int tid = threadIdx.x;
  int wave = tid >> 6, lane = tid & 63;
  int m0 = mt * 128, n0 = nt * 128;
  int kStart = zt * kPerZ;
  int waveM = wave >> 1, waveN = wave & 1;
  int lr = lane >> 2, ch = lane & 3;
  int quad = lane >> 4, mrow = lane & 15;
  int swe = ((quad ^ (mrow & 3)) << 3);

  int rA0 = wave*32 + lr;
  int rA1 = rA0 + 16;
  int ce  = ((ch ^ (rA0 & 3)) << 3);
  const unsigned short* gA0 = A  + (long)(m0 + rA0)*lda + kStart + ce;
  const unsigned short* gA1 = A  + (long)(m0 + rA1)*lda + kStart + ce;
  const unsigned short* gB0 = BT + (long)(n0 + rA0)*ldb + kStart + ce;
  const unsigned short* gB1 = BT + (long)(n0 + rA1)*ldb + kStart + ce;
  unsigned short* lA0 = &As[(wave*32)*32];
  unsigned short* lA1 = &As[(wave*32+16)*32];
  unsigned short* lB0 = &Bs[(wave*32)*32];
  unsigned short* lB1 = &Bs[(wave*32+16)*32];

  f32x4 acc[4][4] = {};
  int nIter = kPerZ >> 5;
  for (int it = 0; it < nIter; ++it){
    long ko = (long)it << 5;
    load_lds16(gA0 + ko, lA0);
    load_lds16(gA1 + ko, lA1);
    load_lds16(gB0 + ko, lB0);
    load_lds16(gB1 + ko, lB1);
    __syncthreads();
    bf16x8 af[4], bfr[4];
#pragma unroll
    for (int mi = 0; mi < 4; mi++)
      af[mi] = *(const bf16x8*)&As[(waveM*64 + mi*16 + mrow)*32 + swe];
#pragma unroll
    for (int ni = 0; ni < 4; ni++)
      bfr[ni] = *(const bf16x8*)&Bs[(waveN*64 + ni*16 + mrow)*32 + swe];
#pragma unroll
    for (int mi = 0; mi < 4; mi++)
#pragma unroll
      for (int ni = 0; ni < 4; ni++)
        acc[mi][ni] = __builtin_amdgcn_mfma_f32_16x16x32_bf16(
            af[mi], bfr[ni], acc[mi][ni], 0, 0, 0);
    __syncthreads();
  }
  if (RELU){
    unsigned short* C = (unsigned short*)Cv;
#pragma unroll
    for (int mi = 0; mi < 4; mi++)
#pragma unroll
      for (int ni = 0; ni < 4; ni++){
        int col = n0 + waveN*64 + ni*16 + mrow;
#pragma unroll
        for (int r = 0; r < 4; r++){
          int row = m0 + waveM*64 + mi*16 + quad*4 + r;
          C[(long)row*ldc + col] = f2bf(fmaxf(acc[mi][ni][r], 0.f));
        }
      }
  } else {
    float* C = (float*)Cv + (long)zt * cStrideZ;
#pragma unroll
    for (int mi = 0; mi < 4; mi++)
#pragma unroll
      for (int ni = 0; ni < 4; ni++){
        int col = n0 + waveN*64 + ni*16 + mrow;
#pragma unroll
        for (int r = 0; r < 4; r++){
          int row = m0 + waveM*64 + mi*16 + quad*4 + r;
          C[(long)row*ldc + col] = acc[mi][ni][r];
        }
      }
  }
}
template __global__ void k_mfma<true>(const unsigned short*, long, const unsigned short*, long, void*, int, int, long, int);
template __global__ void k_mfma<false>(const unsigned short*, long, const unsigned short*, long, void*, int, int, long, int);

// ---------------------------------------------------------------------------
// Region MFMA: g2in[b, z*256+m] = sum_k ARb[b, cum_z+k] * RWT_z[m,k] + regb[z,m]
// grid (8, 2, 10).
// ---------------------------------------------------------------------------
__global__ __launch_bounds__(256) void k_mfma_region(
    const unsigned short* __restrict__ ARb,
    const unsigned short* __restrict__ RWT,
    const float* __restrict__ regb, float* __restrict__ g2in){
  __shared__ unsigned short As[128*32];
  __shared__ unsigned short Bs[128*32];
  int z = blockIdx.z;
  int K = cRegK[z];
  int cumk = cRegCum[z];
  const unsigned short* A  = ARb + cumk;
  const unsigned short* BT = RWT + (long)cumk*256;
  long lda = 7936, ldb = K;
  int tid = threadIdx.x;
  int wave = tid >> 6, lane = tid & 63;
  int m0 = blockIdx.x * 128, n0 = blockIdx.y * 128;
  int waveM = wave >> 1, waveN = wave & 1;
  int lr = lane >> 2, ch = lane & 3;
  int quad = lane >> 4, mrow = lane & 15;
  int swe = ((quad ^ (mrow & 3)) << 3);

  int rA0 = wave*32 + lr;
  int rA1 = rA0 + 16;
  int ce  = ((ch ^ (rA0 & 3)) << 3);
  const unsigned short* gA0 = A  + (long)(m0 + rA0)*lda + ce;
  const unsigned short* gA1 = A  + (long)(m0 + rA1)*lda + ce;
  const unsigned short* gB0 = BT + (long)(n0 + rA0)*ldb + ce;
  const unsigned short* gB1 = BT + (long)(n0 + rA1)*ldb + ce;
  unsigned short* lA0 = &As[(wave*32)*32];
  unsigned short* lA1 = &As[(wave*32+16)*32];
  unsigned short* lB0 = &Bs[(wave*32)*32];
  unsigned short* lB1 = &Bs[(wave*32+16)*32];

  f32x4 acc[4][4] = {};
  int nIter = K >> 5;
  for (int it = 0; it < nIter; ++it){
    long ko = (long)it << 5;
    load_lds16(gA0 + ko, lA0);
    load_lds16(gA1 + ko, lA1);
    load_lds16(gB0 + ko, lB0);
    load_lds16(gB1 + ko, lB1);
    __syncthreads();
    bf16x8 af[4], bfr[4];
#pragma unroll
    for (int mi = 0; mi < 4; mi++)
      af[mi] = *(const bf16x8*)&As[(waveM*64 + mi*16 + mrow)*32 + swe];
#pragma unroll
    for (int ni = 0; ni < 4; ni++)
      bfr[ni] = *(const bf16x8*)&Bs[(waveN*64 + ni*16 + mrow)*32 + swe];
#pragma unroll
    for (int mi = 0; mi < 4; mi++)
#pragma unroll
      for (int ni = 0; ni < 4; ni++)
        acc[mi][ni] = __builtin_amdgcn_mfma_f32_16x16x32_bf16(
            af[mi], bfr[ni], acc[mi][ni], 0, 0, 0);
    __syncthreads();
  }
#pragma unroll
  for (int mi = 0; mi < 4; mi++)
#pragma unroll
    for (int ni = 0; ni < 4; ni++){
      int col = n0 + waveN*64 + ni*16 + mrow;
      float bias = regb[z*256 + col];
#pragma unroll
      for (int r = 0; r < 4; r++){
        int row = m0 + waveM*64 + mi*16 + quad*4 + r;
        g2in[(long)row*2560 + z*256 + col] = acc[mi][ni][r] + bias;
      }
    }
}

// ---------------------------------------------------------------------------
// Merged prep: [0,4784) transpose hc_w1/hc_w2/ch1w/ch2w -> bf16 NxK;
// [4784,7344) region-weight transpose; [7344,7406) A-transpose + (A@A)^T.
// ---------------------------------------------------------------------------
__global__ __launch_bounds__(256) void k_prep_all(
    const float* __restrict__ s0, unsigned short* __restrict__ d0,
    const float* __restrict__ s1, unsigned short* __restrict__ d1,
    const float* __restrict__ s2, unsigned short* __restrict__ d2,
    const float* __restrict__ s3, unsigned short* __restrict__ d3,
    Ptr10 rws, unsigned short* __restrict__ RWT,
    const float* __restrict__ Amat, float* __restrict__ AT,
    float* __restrict__ A2T){
  __shared__ float smem[64*65];
  int id = blockIdx.x;
  int tid = threadIdx.x;
  if (id < 7344 && id >= 4784){
    // region-weight transpose: RWT[cum+m*K + l*128+c] = bf16(rw[m][c*L+l])
    int q = id - 4784;
    int z = q >> 8, m = q & 255;
    int K = cRegK[z], L = K >> 7;
    const float* rw = rws.p[z] + (long)m*K;
    unsigned short* dst = RWT + (long)cRegCum[z]*256 + (long)m*K;
    for (int i = tid; i < K; i += 256) smem[i] = rw[i];
    __syncthreads();
    for (int k = tid; k < K; k += 256){
      int l = k >> 7, c = k & 127;
      dst[k] = f2bf(smem[c*L + l]);
    }
    return;
  }
  if (id >= 7344){
    // A helpers, one row per block
    int r = id - 7344, c = tid;
    if (c < 62) smem[c] = Amat[r*62 + c];
    __syncthreads();
    if (c < 62){
      AT[c*62 + r] = smem[c];
      float s = 0.f;
      for (int t = 0; t < 62; t++) s = fmaf(smem[t], Amat[t*62 + c], s);
      A2T[c*62 + r] = s;
    }
    return;
  }
  // 64x64 fp32->bf16 transpose tiles
  const float* src; unsigned short* dst; int R, C, rt, ct;
  if (id < 4608){ src=s0; dst=d0; R=36864; C=512; rt=id>>3;  ct=id&7; }
  else if (id < 4640){ int q=id-4608; src=s1; dst=d1; R=512; C=256; rt=q>>2; ct=q&3; }
  else if (id < 4688){ int q=id-4640; src=s2; dst=d2; R=384; C=512; rt=q>>3; ct=q&7; }
  else { int q=id-4688; src=s3; dst=d3; R=768; C=512; rt=q>>3; ct=q&7; }
  int r0 = rt*64, c0 = ct*64;
  int rr = tid >> 2, cb = (tid & 3) << 2;
#pragma unroll
  for (int i = 0; i < 4; i++){
    int cc = cb + i*16;
    float4 v = *(const float4*)(src + (long)(r0+rr)*C + c0 + cc);
    smem[rr*65+cc+0]=v.x; smem[rr*65+cc+1]=v.y;
    smem[rr*65+cc+2]=v.z; smem[rr*65+cc+3]=v.w;
  }
  __syncthreads();
  int cc = tid >> 2, rb = (tid & 3) << 2;
#pragma unroll
  for (int i = 0; i < 4; i++){
    int r = rb + i*16;
    ushort4 u = make_ushort4(f2bf(smem[(r+0)*65+cc]), f2bf(smem[(r+1)*65+cc]),
                             f2bf(smem[(r+2)*65+cc]), f2bf(smem[(r+3)*65+cc]));
    *(ushort4*)(dst + (long)(c0+cc)*R + r0 + r) = u;
  }
}

// ---------------------------------------------------------------------------
// 1+2 fused: per block b: g[n,c] = (x.tfe + tb)*exp(-var) (ddof=1), then
// XCAT slots 0/1/2 = bf16(g / A@g / A^2@g), ARb = permuted bf16 g.
// ---------------------------------------------------------------------------
__global__ __launch_bounds__(256) void k_gspread(
    const float* __restrict__ x, const float* __restrict__ tw,
    const float* __restrict__ tb, const float* __restrict__ AT,
    const float* __restrict__ A2T, unsigned short* __restrict__ arb,
    unsigned short* __restrict__ xcat){
  __shared__ float sgn[7936];
  int b = blockIdx.x, tid = threadIdx.x;
  int c = tid & 127, half = tid >> 7;
  const float* xb = x + (long)b * 79360;
  for (int nn = 0; nn < 31; nn++){
    int n = nn*2 + half;
    const float* xp = xb + (long)n*1280 + c;
    float s = 0.f, s2 = 0.f, gv = 0.f;
#pragma unroll
    for (int i = 0; i < 10; i++){
      float v = xp[i*128];
      s += v; s2 = fmaf(v, v, s2);
      gv = fmaf(v, tw[n*10 + i], gv);
    }
    float mean = s * 0.1f;
    float var  = (s2 - 10.f*mean*mean) * (1.f/9.f);
    float res  = (gv + tb[n]) * expf(-var);
    sgn[n*128 + c] = res;
    unsigned short rb = f2bf(res);
    arb[(long)b*7936 + cPos[n]*128 + c] = rb;
    xcat[(long)b*23808 + n*384 + c]     = rb;
  }
  __syncthreads();
  const float* MT = half ? A2T : AT;
  float acc[62];
#pragma unroll
  for (int n = 0; n < 62; n++) acc[n] = 0.f;
  for (int m = 0; m < 62; m++){
    float gv = sgn[m*128 + c];
    const float* Mp = MT + m*62;        // wave-uniform -> scalar loads
#pragma unroll
    for (int n = 0; n < 62; n++) acc[n] = fmaf(Mp[n], gv, acc[n]);
  }
  long base = (long)b*23808 + (half+1)*128 + c;
#pragma unroll
  for (int n = 0; n < 62; n++) xcat[base + (long)n*384] = f2bf(acc[n]);
}

// ---------------------------------------------------------------------------
// 4) X2cat[b, n, k*256+t] = (A1^k @ g2in[b])[n,t], k=0..2  (bf16 out)
// ---------------------------------------------------------------------------
__global__ __launch_bounds__(256) void k_x2cat(
    const float* __restrict__ g2in, const float* __restrict__ A1,
    unsigned short* __restrict__ X2){
  __shared__ float sg[2560];
  __shared__ float sA1[100];
  __shared__ float sA2[100];
  int b = blockIdx.x, tid = threadIdx.x;
  for (int i = tid; i < 2560; i += 256) sg[i] = g2in[(long)b*2560 + i];
  if (tid < 100) sA1[tid] = A1[tid];
  __syncthreads();
  if (tid < 100){
    int n = tid/10, m = tid - n*10;
    float a = 0.f;
#pragma unroll
    for (int t = 0; t < 10; t++) a = fmaf(sA1[n*10+t], sA1[t*10+m], a);
    sA2[tid] = a;
  }
  __syncthreads();
  for (int i = tid; i < 2560; i += 256){
    int n = i >> 8, t = i & 255;
    float v1 = 0.f, v2 = 0.f;
#pragma unroll
    for (int m = 0; m < 10; m++){
      float gv = sg[(m<<8) + t];
      v1 = fmaf(sA1[n*10+m], gv, v1);
      v2 = fmaf(sA2[n*10+m], gv, v2);
    }
    long base = (long)b*7680 + n*768;
    X2[base + t]       = f2bf(sg[i]);
    X2[base + 256 + t] = f2bf(v1);
    X2[base + 512 + t] = f2bf(v2);
  }
}

// ---------------------------------------------------------------------------
// 6) softmax-gated concat. exp computed once: sc overwritten with e*v.
// ---------------------------------------------------------------------------
__global__ __launch_bounds__(128) void k_softcat(
    const unsigned short* __restrict__ g1, const unsigned short* __restrict__ g2,
    const float* __restrict__ bg_, const float* __restrict__ cg_,
    unsigned short* __restrict__ outb){
  __shared__ float sc[72][128];
  int b = blockIdx.x;
  int oq = blockIdx.y * 128;
  int tid = threadIdx.x;
  int o = oq + tid;
#pragma unroll
  for (int j = 0; j < 62; j++) sc[j][tid] = bf2f(g1[((long)b*62 + j)*512 + o]);
#pragma unroll
  for (int j = 0; j < 10; j++) sc[62+j][tid] = bf2f(g2[((long)b*10 + j)*512 + o]);
  __syncthreads();
  float bg = *bg_, cg = *cg_;
  float mx = -1e30f;
#pragma unroll
  for (int j = 0; j < 72; j++){
    float av = (j < 62 ? bg : cg) * sc[j][tid];
    mx = fmaxf(mx, av);
  }
  float sum = 0.f;
#pragma unroll
  for (int j = 0; j < 72; j++){
    float v = sc[j][tid];
    float e = expf((j < 62 ? bg : cg) * v - mx);
    sum += e;
    sc[j][tid] = e * v;
  }
  float inv = 1.f / sum;
#pragma unroll
  for (int j = 0; j < 72; j++)
    outb[(long)b*36864 + j*512 + o] = f2bf(sc[j][tid] * inv);
}

// 8) reduce 16 split-K partials -> h1 (1024 x 512) fp32, float4
__global__ __launch_bounds__(256) void k_reduce(
    const float4* __restrict__ P, float4* __restrict__ h1){
  int idx = blockIdx.x*256 + threadIdx.x;   // 0 .. 131071
  float4 v = make_float4(0.f,0.f,0.f,0.f);
#pragma unroll
  for (int s = 0; s < 16; s++){
    float4 p = P[(long)s*131072 + idx];
    v.x += p.x; v.y += p.y; v.z += p.z; v.w += p.w;
  }
  h1[idx] = v;
}

// 9) batch-norm stats (ddof=0), 8 columns per block
template<int N>
__global__ __launch_bounds__(256) void k_stats(
    const float* __restrict__ h, float* __restrict__ mu, float* __restrict__ rs){
  __shared__ float ls[256], ls2[256];
  int j0 = blockIdx.x * 8;
  int jj = threadIdx.x & 7, bg = threadIdx.x >> 3;
  float s = 0.f, s2 = 0.f;
#pragma unroll 4
  for (int it = 0; it < 32; it++){
    float v = h[(long)(it*32 + bg)*N + j0 + jj];
    s += v; s2 = fmaf(v, v, s2);
  }
  ls[threadIdx.x] = s; ls2[threadIdx.x] = s2;
  __syncthreads();
  if (threadIdx.x < 8){
    float a = ls[threadIdx.x], a2 = ls2[threadIdx.x];
    for (int g = 1; g < 32; g++){ a += ls[g*8 + threadIdx.x]; a2 += ls2[g*8 + threadIdx.x]; }
    float m = a * (1.f/1024.f);
    float var = a2 * (1.f/1024.f) - m*m;
    mu[j0 + threadIdx.x] = m;
    rs[j0 + threadIdx.x] = rsqrtf(var + 1e-5f);
  }
}

// 9b) H1B = bf16(gelu(bn1(h1)))   (1024x512)
__global__ __launch_bounds__(256) void k_bngelu(
    const float* __restrict__ h1, const float* __restrict__ mu,
    const float* __restrict__ rs, const float* __restrict__ gam,
    const float* __restrict__ bet, unsigned short* __restrict__ h1b){
  int base = (blockIdx.x*256 + threadIdx.x) * 4;
  int j = base & 511;
  float4 v = *(const float4*)(h1 + base);
  ushort4 u;
  u.x = f2bf(gelu_exact((v.x - mu[j+0])*rs[j+0]*gam[j+0] + bet[j+0]));
  u.y = f2bf(gelu_exact((v.y - mu[j+1])*rs[j+1]*gam[j+1] + bet[j+1]));
  u.z = f2bf(gelu_exact((v.z - mu[j+2])*rs[j+2]*gam[j+2] + bet[j+2]));
  u.w = f2bf(gelu_exact((v.w - mu[j+3])*rs[j+3]*gam[j+3] + bet[j+3]));
  *(ushort4*)(h1b + base) = u;
}

// 11) final: bn2+gelu, @ hc_w3 + hc_b3, softmax over 4 -> d_out
__global__ __launch_bounds__(256) void k_final(
    const float* __restrict__ h2, const float* __restrict__ mu,
    const float* __restrict__ rs, const float* __restrict__ gam,
    const float* __restrict__ bet, const float* __restrict__ w3,
    const float* __restrict__ b3, float* __restrict__ outp){
  int b = blockIdx.x, tid = threadIdx.x;
  float v = h2[(long)b*256 + tid];
  v = (v - mu[tid]) * rs[tid] * gam[tid] + bet[tid];
  v = gelu_exact(v);
  float4 w = ((const float4*)w3)[tid];
  float p0 = v*w.x, p1 = v*w.y, p2 = v*w.z, p3 = v*w.w;
#pragma unroll
  for (int o = 32; o > 0; o >>= 1){
    p0 += __shfl_down(p0, o);
    p1 += __shfl_down(p1, o);
    p2 += __shfl_down(p2, o);
    p3 += __shfl_down(p3, o);
  }
  __shared__ float red[4][4];
  int wv = tid >> 6;
  if ((tid & 63) == 0){ red[wv][0]=p0; red[wv][1]=p1; red[wv][2]=p2; red[wv][3]=p3; }
  __syncthreads();
  if (tid == 0){
    float l[4];
#pragma unroll
    for (int c = 0; c < 4; c++)
      l[c] = red[0][c]+red[1][c]+red[2][c]+red[3][c] + b3[c];
    float m = fmaxf(fmaxf(l[0], l[1]), fmaxf(l[2], l[3]));
    float e[4]; float sum = 0.f;
#pragma unroll
    for (int c = 0; c < 4; c++){ e[c] = expf(l[c]-m); sum += e[c]; }
    float inv = 1.f / sum;
#pragma unroll
    for (int c = 0; c < 4; c++) outp[(long)b*4 + c] = e[c]*inv;
  }
}

// ---------------------------------------------------------------------------
// Workspace layout (byte offsets), peak ~248 MB (same as round 4).
// ---------------------------------------------------------------------------
extern "C" void kernel_launch(void* const* d_in, const int* in_sizes, int n_in,
                              void* d_out, int out_size, void* d_ws, size_t ws_size,
                              hipStream_t stream){
  (void)n_in; (void)out_size; (void)ws_size;
  bool dictOrder = (in_sizes[9] == 2560);
  const float* x     = (const float*)d_in[0];
  const float* tfe_w = (const float*)d_in[1];
  const float* tfe_b = (const float*)d_in[2];
  const float* ch1w  = (const float*)d_in[3];
  const float* Amat  = (const float*)d_in[4];
  const float* ch2w  = (const float*)d_in[5];
  const float* A1mat = (const float*)d_in[6];
  const float* bgate = (const float*)d_in[7];
  const float* cgate = (const float*)d_in[8];
  const float* regb  = (const float*)d_in[dictOrder ? 9 : 19];
  int o = dictOrder ? 0 : 10;
  const float* hc_w1 = (const float*)d_in[10+o];
  const float* bn1g  = (const float*)d_in[12+o];
  const float* bn1b  = (const float*)d_in[13+o];
  const float* hc_w2 = (const float*)d_in[14+o];
  const float* bn2g  = (const float*)d_in[16+o];
  const float* bn2b  = (const float*)d_in[17+o];
  const float* hc_w3 = (const float*)d_in[18+o];
  const float* hc_b3 = (const float*)d_in[19+o];
  Ptr10 rws;
  for (int i = 0; i < 10; i++) rws.p[i] = (const float*)d_in[(dictOrder ? 20 : 9) + i];

  char* Wb = (char*)d_ws;
  unsigned short* ARb   = (unsigned short*)(Wb + 0);
  unsigned short* XCAT  = (unsigned short*)(Wb + 16252928);
  unsigned short* RWT   = (unsigned short*)(Wb + 65011712);
  float*          G2IN  = (float*)(Wb + 69074944);
  unsigned short* X2CAT = (unsigned short*)(Wb + 79560704);
  unsigned short* W1T   = (unsigned short*)(Wb + 95289344);
  unsigned short* WC1T  = (unsigned short*)(Wb + 133038080);
  unsigned short* WC2T  = (unsigned short*)(Wb + 133431296);
  unsigned short* G1    = (unsigned short*)(Wb + 134217728);
  unsigned short* G2    = (unsigned short*)(Wb + 199229440);
  unsigned short* OUTB  = (unsigned short*)(Wb + 0);
  float*          P     = (float*)(Wb + 209715200);
  float*          H1    = (float*)(Wb + 243269632);
  float*          H2    = (float*)(Wb + 245366784);
  float*          MU1   = (float*)(Wb + 246415360);
  float*          RS1   = MU1 + 512;
  float*          MU2   = MU1 + 1024;
  float*          RS2   = MU1 + 1280;
  float*          AT    = (float*)(Wb + 246423552);
  float*          A2T   = (float*)(Wb + 246439040);
  unsigned short* W2T   = (unsigned short*)(Wb + 246454528);
  unsigned short* H1B   = (unsigned short*)(Wb + 246716928);

  // prep: all weight transforms in one launch
  k_prep_all<<<7406, 256, 0, stream>>>(hc_w1, W1T, hc_w2, W2T, ch1w, WC1T,
                                       ch2w, WC2T, rws, RWT, Amat, AT, A2T);
  // g + both spread hops fused (one block per b)
  k_gspread<<<1024, 256, 0, stream>>>(x, tfe_w, tfe_b, AT, A2T, ARb, XCAT);
  k_mfma_region<<<dim3(8,2,10), 256, 0, stream>>>(ARb, RWT, regb, G2IN);
  k_x2cat<<<1024, 256, 0, stream>>>(G2IN, A1mat, X2CAT);
  // cheby2: (10240 x 768) @ (768 x 512), swizzled 320 blocks (mc=40)
  k_mfma<true><<<320, 256, 0, stream>>>(X2CAT, 768, WC2T, 768, (void*)G2, 512, 768, 0, 40);
  // cheby1: (63488 x 384) @ (384 x 512), swizzled 1984 blocks (mc=248)
  k_mfma<true><<<1984, 256, 0, stream>>>(XCAT, 384, WC1T, 384, (void*)G1, 512, 384, 0, 248);
  k_softcat<<<dim3(1024,4), 128, 0, stream>>>(G1, G2, bgate, cgate, OUTB);
  // h1: (1024 x 36864) @ (36864 x 512), split-K=16, swizzled 512 blocks (mc=4)
  k_mfma<false><<<512, 256, 0, stream>>>(OUTB, 36864, W1T, 36864, (void*)P, 512, 2304, 524288, 4);
  k_reduce<<<512, 256, 0, stream>>>((const float4*)P, (float4*)H1);
  k_stats<512><<<64, 256, 0, stream>>>(H1, MU1, RS1);
  k_bngelu<<<512, 256, 0, stream>>>(H1, MU1, RS1, bn1g, bn1b, H1B);
  // h2: (1024 x 512) @ (512 x 256), plain grid
  k_mfma<false><<<dim3(8,2,1), 256, 0, stream>>>(H1B, 512, W2T, 512, (void*)H2, 256, 512, 0, 0);
  k_stats<256><<<32, 256, 0, stream>>>(H2, MU2, RS2);
  k_final<<<1024, 256, 0, stream>>>(H2, MU2, RS2, bn2g, bn2b, hc_w3, hc_b3, (float*)d_out);
}

// Round 6
// 924.248 us; speedup vs baseline: 1.0303x; 1.0303x over previous
//
#include <hip/hip_runtime.h>
#include <math.h>

// ---------------------------------------------------------------------------
// Problem constants: B=1024, XDIM=62, TWIN=10, INCH=128, MID=256, OUT=512,
// K=3, K1=10, LIN=512.  REGIONS partition nodes 0..61 exactly once.
// hc_b1/hc_b2 dropped: BN subtracts the batch mean -> bias-invariant.
// ---------------------------------------------------------------------------

// concat order of nodes (p -> node)
__constant__ int cOrder[62] = {
  0,1,2,3,4,
  5,6,7,14,15,16,
  8,9,10,17,18,19,
  11,12,13,20,21,22,
  23,24,25,32,33,34,
  26,27,28,35,36,37,
  29,30,31,38,39,40,
  41,42,43,50,51,57,
  44,45,46,52,53,54,58,59,60,
  47,48,49,55,56,61
};
// node -> position in concat order
__constant__ int cPos[62] = {
  0,1,2,3,4, 5,6,7, 11,12,13, 17,18,19, 8,9,10, 14,15,16, 20,21,22,
  23,24,25, 29,30,31, 35,36,37, 26,27,28, 32,33,34, 38,39,40,
  41,42,43, 47,48,49, 56,57,58, 44,45, 50,51,52, 59,60, 46, 53,54,55, 61
};
// per-region K (=L*128) and cumulative k offset
__constant__ int cRegK[10]   = {640,768,768,768,768,768,768,768,1152,768};
__constant__ int cRegCum[10] = {0,640,1408,2176,2944,3712,4480,5248,6016,7168};

struct Ptr10 { const float* p[10]; };

typedef __attribute__((ext_vector_type(8))) short bf16x8;
typedef __attribute__((ext_vector_type(4))) float f32x4;

__device__ __forceinline__ float gelu_exact(float v){
  return 0.5f * v * (1.0f + erff(v * 0.70710678118654752f));
}
__device__ __forceinline__ unsigned short f2bf(float f){
  unsigned u = __float_as_uint(f);
  unsigned r = (u + 0x7fffu + ((u >> 16) & 1u)) >> 16;
  return (unsigned short)r;
}
__device__ __forceinline__ float bf2f(unsigned short u){
  return __uint_as_float(((unsigned)u) << 16);
}
__device__ __forceinline__ void load_lds16(const unsigned short* g, unsigned short* l){
  __builtin_amdgcn_global_load_lds(
      (const __attribute__((address_space(1))) void*)g,
      (__attribute__((address_space(3))) void*)l, 16, 0, 0);
}

// ---------------------------------------------------------------------------
// MFMA GEMM: C(MxN) = A(MxK) @ BT(NxK)^T, bf16 in, fp32 acc. 128x128 tile,
// BK=32, XOR-swizzled LDS, global_load_lds w=16.
// mcCount>0: 1-D grid with XCD-cluster swizzle (2m x 4n clusters per XCD).
// mcCount==0: plain 3-D grid. RELU=true: bf16+relu store; else fp32 partial.
// ---------------------------------------------------------------------------
template<bool RELU>
__global__ __launch_bounds__(256) void k_mfma(
    const unsigned short* __restrict__ A, long lda,
    const unsigned short* __restrict__ BT, long ldb,
    void* __restrict__ Cv, int ldc, int kPerZ, long cStrideZ, int mcCount){
  __shared__ unsigned short As[128*32];
  __shared__ unsigned short Bs[128*32];
  int mt, nt, zt;
  if (mcCount){
    int id = blockIdx.x;
    int c = ((id >> 6) << 3) + (id & 7);   // cluster index
    int member = (id >> 3) & 7;
    zt = c / mcCount;
    int mc = c - zt*mcCount;
    mt = mc*2 + (member >> 2);
    nt = member & 3;
  } else { mt = blockIdx.x; nt = blockIdx.y; zt = blockIdx.z; }
  int tid = threadIdx.x;
  int wave = tid >> 6, lane = tid & 63;
  int m0 = mt * 128, n0 = nt * 128;
  int kStart = zt * kPerZ;
  int waveM = wave >> 1, waveN = wave & 1;
  int lr = lane >> 2, ch = lane & 3;
  int quad = lane >> 4, mrow = lane & 15;
  int swe = ((quad ^ (mrow & 3)) << 3);

  int rA0 = wave*32 + lr;
  int rA1 = rA0 + 16;
  int ce  = ((ch ^ (rA0 & 3)) << 3);
  const unsigned short* gA0 = A  + (long)(m0 + rA0)*lda + kStart + ce;
  const unsigned short* gA1 = A  + (long)(m0 + rA1)*lda + kStart + ce;
  const unsigned short* gB0 = BT + (long)(n0 + rA0)*ldb + kStart + ce;
  const unsigned short* gB1 = BT + (long)(n0 + rA1)*ldb + kStart + ce;
  unsigned short* lA0 = &As[(wave*32)*32];
  unsigned short* lA1 = &As[(wave*32+16)*32];
  unsigned short* lB0 = &Bs[(wave*32)*32];
  unsigned short* lB1 = &Bs[(wave*32+16)*32];

  f32x4 acc[4][4] = {};
  int nIter = kPerZ >> 5;
  for (int it = 0; it < nIter; ++it){
    long ko = (long)it << 5;
    load_lds16(gA0 + ko, lA0);
    load_lds16(gA1 + ko, lA1);
    load_lds16(gB0 + ko, lB0);
    load_lds16(gB1 + ko, lB1);
    __syncthreads();
    bf16x8 af[4], bfr[4];
#pragma unroll
    for (int mi = 0; mi < 4; mi++)
      af[mi] = *(const bf16x8*)&As[(waveM*64 + mi*16 + mrow)*32 + swe];
#pragma unroll
    for (int ni = 0; ni < 4; ni++)
      bfr[ni] = *(const bf16x8*)&Bs[(waveN*64 + ni*16 + mrow)*32 + swe];
#pragma unroll
    for (int mi = 0; mi < 4; mi++)
#pragma unroll
      for (int ni = 0; ni < 4; ni++)
        acc[mi][ni] = __builtin_amdgcn_mfma_f32_16x16x32_bf16(
            af[mi], bfr[ni], acc[mi][ni], 0, 0, 0);
    __syncthreads();
  }
  if (RELU){
    unsigned short* C = (unsigned short*)Cv;
#pragma unroll
    for (int mi = 0; mi < 4; mi++)
#pragma unroll
      for (int ni = 0; ni < 4; ni++){
        int col = n0 + waveN*64 + ni*16 + mrow;
#pragma unroll
        for (int r = 0; r < 4; r++){
          int row = m0 + waveM*64 + mi*16 + quad*4 + r;
          C[(long)row*ldc + col] = f2bf(fmaxf(acc[mi][ni][r], 0.f));
        }
      }
  } else {
    float* C = (float*)Cv + (long)zt * cStrideZ;
#pragma unroll
    for (int mi = 0; mi < 4; mi++)
#pragma unroll
      for (int ni = 0; ni < 4; ni++){
        int col = n0 + waveN*64 + ni*16 + mrow;
#pragma unroll
        for (int r = 0; r < 4; r++){
          int row = m0 + waveM*64 + mi*16 + quad*4 + r;
          C[(long)row*ldc + col] = acc[mi][ni][r];
        }
      }
  }
}
template __global__ void k_mfma<true>(const unsigned short*, long, const unsigned short*, long, void*, int, int, long, int);
template __global__ void k_mfma<false>(const unsigned short*, long, const unsigned short*, long, void*, int, int, long, int);

// ---------------------------------------------------------------------------
// Region MFMA: g2in[b, z*256+m] = sum_k ARb[b, cum_z+k] * RWT_z[m,k] + regb[z,m]
// grid (8, 2, 10).
// ---------------------------------------------------------------------------
__global__ __launch_bounds__(256) void k_mfma_region(
    const unsigned short* __restrict__ ARb,
    const unsigned short* __restrict__ RWT,
    const float* __restrict__ regb, float* __restrict__ g2in){
  __shared__ unsigned short As[128*32];
  __shared__ unsigned short Bs[128*32];
  int z = blockIdx.z;
  int K = cRegK[z];
  int cumk = cRegCum[z];
  const unsigned short* A  = ARb + cumk;
  const unsigned short* BT = RWT + (long)cumk*256;
  long lda = 7936, ldb = K;
  int tid = threadIdx.x;
  int wave = tid >> 6, lane = tid & 63;
  int m0 = blockIdx.x * 128, n0 = blockIdx.y * 128;
  int waveM = wave >> 1, waveN = wave & 1;
  int lr = lane >> 2, ch = lane & 3;
  int quad = lane >> 4, mrow = lane & 15;
  int swe = ((quad ^ (mrow & 3)) << 3);

  int rA0 = wave*32 + lr;
  int rA1 = rA0 + 16;
  int ce  = ((ch ^ (rA0 & 3)) << 3);
  const unsigned short* gA0 = A  + (long)(m0 + rA0)*lda + ce;
  const unsigned short* gA1 = A  + (long)(m0 + rA1)*lda + ce;
  const unsigned short* gB0 = BT + (long)(n0 + rA0)*ldb + ce;
  const unsigned short* gB1 = BT + (long)(n0 + rA1)*ldb + ce;
  unsigned short* lA0 = &As[(wave*32)*32];
  unsigned short* lA1 = &As[(wave*32+16)*32];
  unsigned short* lB0 = &Bs[(wave*32)*32];
  unsigned short* lB1 = &Bs[(wave*32+16)*32];

  f32x4 acc[4][4] = {};
  int nIter = K >> 5;
  for (int it = 0; it < nIter; ++it){
    long ko = (long)it << 5;
    load_lds16(gA0 + ko, lA0);
    load_lds16(gA1 + ko, lA1);
    load_lds16(gB0 + ko, lB0);
    load_lds16(gB1 + ko, lB1);
    __syncthreads();
    bf16x8 af[4], bfr[4];
#pragma unroll
    for (int mi = 0; mi < 4; mi++)
      af[mi] = *(const bf16x8*)&As[(waveM*64 + mi*16 + mrow)*32 + swe];
#pragma unroll
    for (int ni = 0; ni < 4; ni++)
      bfr[ni] = *(const bf16x8*)&Bs[(waveN*64 + ni*16 + mrow)*32 + swe];
#pragma unroll
    for (int mi = 0; mi < 4; mi++)
#pragma unroll
      for (int ni = 0; ni < 4; ni++)
        acc[mi][ni] = __builtin_amdgcn_mfma_f32_16x16x32_bf16(
            af[mi], bfr[ni], acc[mi][ni], 0, 0, 0);
    __syncthreads();
  }
#pragma unroll
  for (int mi = 0; mi < 4; mi++)
#pragma unroll
    for (int ni = 0; ni < 4; ni++){
      int col = n0 + waveN*64 + ni*16 + mrow;
      float bias = regb[z*256 + col];
#pragma unroll
      for (int r = 0; r < 4; r++){
        int row = m0 + waveM*64 + mi*16 + quad*4 + r;
        g2in[(long)row*2560 + z*256 + col] = acc[mi][ni][r] + bias;
      }
    }
}

// ---------------------------------------------------------------------------
// Merged prep: [0,4784) transpose hc_w1/hc_w2/ch1w/ch2w -> bf16 NxK;
// [4784,7344) region-weight transpose; [7344,7406) A-transpose + (A@A)^T.
// ---------------------------------------------------------------------------
__global__ __launch_bounds__(256) void k_prep_all(
    const float* __restrict__ s0, unsigned short* __restrict__ d0,
    const float* __restrict__ s1, unsigned short* __restrict__ d1,
    const float* __restrict__ s2, unsigned short* __restrict__ d2,
    const float* __restrict__ s3, unsigned short* __restrict__ d3,
    Ptr10 rws, unsigned short* __restrict__ RWT,
    const float* __restrict__ Amat, float* __restrict__ AT,
    float* __restrict__ A2T){
  __shared__ float smem[64*65];
  int id = blockIdx.x;
  int tid = threadIdx.x;
  if (id < 7344 && id >= 4784){
    // region-weight transpose: RWT[cum+m*K + l*128+c] = bf16(rw[m][c*L+l])
    int q = id - 4784;
    int z = q >> 8, m = q & 255;
    int K = cRegK[z], L = K >> 7;
    const float* rw = rws.p[z] + (long)m*K;
    unsigned short* dst = RWT + (long)cRegCum[z]*256 + (long)m*K;
    for (int i = tid; i < K; i += 256) smem[i] = rw[i];
    __syncthreads();
    for (int k = tid; k < K; k += 256){
      int l = k >> 7, c = k & 127;
      dst[k] = f2bf(smem[c*L + l]);
    }
    return;
  }
  if (id >= 7344){
    // A helpers, one row per block
    int r = id - 7344, c = tid;
    if (c < 62) smem[c] = Amat[r*62 + c];
    __syncthreads();
    if (c < 62){
      AT[c*62 + r] = smem[c];
      float s = 0.f;
      for (int t = 0; t < 62; t++) s = fmaf(smem[t], Amat[t*62 + c], s);
      A2T[c*62 + r] = s;
    }
    return;
  }
  // 64x64 fp32->bf16 transpose tiles
  const float* src; unsigned short* dst; int R, C, rt, ct;
  if (id < 4608){ src=s0; dst=d0; R=36864; C=512; rt=id>>3;  ct=id&7; }
  else if (id < 4640){ int q=id-4608; src=s1; dst=d1; R=512; C=256; rt=q>>2; ct=q&3; }
  else if (id < 4688){ int q=id-4640; src=s2; dst=d2; R=384; C=512; rt=q>>3; ct=q&7; }
  else { int q=id-4688; src=s3; dst=d3; R=768; C=512; rt=q>>3; ct=q&7; }
  int r0 = rt*64, c0 = ct*64;
  int rr = tid >> 2, cb = (tid & 3) << 2;
#pragma unroll
  for (int i = 0; i < 4; i++){
    int cc = cb + i*16;
    float4 v = *(const float4*)(src + (long)(r0+rr)*C + c0 + cc);
    smem[rr*65+cc+0]=v.x; smem[rr*65+cc+1]=v.y;
    smem[rr*65+cc+2]=v.z; smem[rr*65+cc+3]=v.w;
  }
  __syncthreads();
  int cc = tid >> 2, rb = (tid & 3) << 2;
#pragma unroll
  for (int i = 0; i < 4; i++){
    int r = rb + i*16;
    ushort4 u = make_ushort4(f2bf(smem[(r+0)*65+cc]), f2bf(smem[(r+1)*65+cc]),
                             f2bf(smem[(r+2)*65+cc]), f2bf(smem[(r+3)*65+cc]));
    *(ushort4*)(dst + (long)(c0+cc)*R + r0 + r) = u;
  }
}

// ---------------------------------------------------------------------------
// 1) g[b,n,c] = (sum_i x[b,n,i,c]*tfe_w[n,i] + tfe_b[n]) * exp(-var_i(x)) (ddof=1)
//    -> ARb bf16 [b][pos(n)*128+c] and XCAT slot0 bf16. 63488 blocks: HBM-bound.
// ---------------------------------------------------------------------------
__global__ __launch_bounds__(128) void k_g(
    const float* __restrict__ x, const float* __restrict__ tw,
    const float* __restrict__ tb, unsigned short* __restrict__ arb,
    unsigned short* __restrict__ xcat){
  int bid = blockIdx.x;            // b*62 + n
  int b = bid / 62, n = bid - b*62;
  int t = threadIdx.x;             // channel
  const float* xp = x + (long)bid * 1280 + t;
  float s = 0.f, s2 = 0.f, gv = 0.f;
#pragma unroll
  for (int i = 0; i < 10; i++){
    float v = xp[(long)i*128];
    s += v; s2 = fmaf(v, v, s2);
    gv = fmaf(v, tw[n*10 + i], gv);
  }
  float mean = s * 0.1f;
  float var  = (s2 - 10.f*mean*mean) * (1.f/9.f);
  float res  = (gv + tb[n]) * expf(-var);
  unsigned short rb = f2bf(res);
  arb[(long)b*7936 + cPos[n]*128 + t] = rb;
  xcat[(long)b*23808 + n*384 + t]     = rb;
}

// ---------------------------------------------------------------------------
// 2) fused spread: XCAT slot1 = bf16(A @ g_b), slot2 = bf16(A^2 @ g_b).
//    One block per b; 256 thr = 128 c x 2 mats; A rows via uniform scalar loads.
// ---------------------------------------------------------------------------
__global__ __launch_bounds__(256) void k_spread2(
    const unsigned short* __restrict__ ARb, const float* __restrict__ AT,
    const float* __restrict__ A2T, unsigned short* __restrict__ xcat){
  __shared__ float sgn[7936];
  int b = blockIdx.x, tid = threadIdx.x;
  for (int i = tid; i < 7936; i += 256){
    int p = i >> 7, c = i & 127;
    sgn[cOrder[p]*128 + c] = bf2f(ARb[(long)b*7936 + i]);
  }
  __syncthreads();
  int c = tid & 127, mat = tid >> 7;      // mat uniform per wave
  const float* MT = mat ? A2T : AT;
  float acc[62];
#pragma unroll
  for (int n = 0; n < 62; n++) acc[n] = 0.f;
  for (int m = 0; m < 62; m++){
    float gv = sgn[m*128 + c];
    const float* Mp = MT + m*62;          // contiguous row -> scalar loads
#pragma unroll
    for (int n = 0; n < 62; n++) acc[n] = fmaf(Mp[n], gv, acc[n]);
  }
  long base = (long)b*23808 + (mat+1)*128 + c;
#pragma unroll
  for (int n = 0; n < 62; n++) xcat[base + (long)n*384] = f2bf(acc[n]);
}

// ---------------------------------------------------------------------------
// 4) X2cat[b, n, k*256+t] = (A1^k @ g2in[b])[n,t], k=0..2  (bf16 out)
// ---------------------------------------------------------------------------
__global__ __launch_bounds__(256) void k_x2cat(
    const float* __restrict__ g2in, const float* __restrict__ A1,
    unsigned short* __restrict__ X2){
  __shared__ float sg[2560];
  __shared__ float sA1[100];
  __shared__ float sA2[100];
  int b = blockIdx.x, tid = threadIdx.x;
  for (int i = tid; i < 2560; i += 256) sg[i] = g2in[(long)b*2560 + i];
  if (tid < 100) sA1[tid] = A1[tid];
  __syncthreads();
  if (tid < 100){
    int n = tid/10, m = tid - n*10;
    float a = 0.f;
#pragma unroll
    for (int t = 0; t < 10; t++) a = fmaf(sA1[n*10+t], sA1[t*10+m], a);
    sA2[tid] = a;
  }
  __syncthreads();
  for (int i = tid; i < 2560; i += 256){
    int n = i >> 8, t = i & 255;
    float v1 = 0.f, v2 = 0.f;
#pragma unroll
    for (int m = 0; m < 10; m++){
      float gv = sg[(m<<8) + t];
      v1 = fmaf(sA1[n*10+m], gv, v1);
      v2 = fmaf(sA2[n*10+m], gv, v2);
    }
    long base = (long)b*7680 + n*768;
    X2[base + t]       = f2bf(sg[i]);
    X2[base + 256 + t] = f2bf(v1);
    X2[base + 512 + t] = f2bf(v2);
  }
}

// ---------------------------------------------------------------------------
// 6) softmax-gated concat. exp computed once: sc overwritten with e*v.
// ---------------------------------------------------------------------------
__global__ __launch_bounds__(128) void k_softcat(
    const unsigned short* __restrict__ g1, const unsigned short* __restrict__ g2,
    const float* __restrict__ bg_, const float* __restrict__ cg_,
    unsigned short* __restrict__ outb){
  __shared__ float sc[72][128];
  int b = blockIdx.x;
  int oq = blockIdx.y * 128;
  int tid = threadIdx.x;
  int o = oq + tid;
#pragma unroll
  for (int j = 0; j < 62; j++) sc[j][tid] = bf2f(g1[((long)b*62 + j)*512 + o]);
#pragma unroll
  for (int j = 0; j < 10; j++) sc[62+j][tid] = bf2f(g2[((long)b*10 + j)*512 + o]);
  __syncthreads();
  float bg = *bg_, cg = *cg_;
  float mx = -1e30f;
#pragma unroll
  for (int j = 0; j < 72; j++){
    float av = (j < 62 ? bg : cg) * sc[j][tid];
    mx = fmaxf(mx, av);
  }
  float sum = 0.f;
#pragma unroll
  for (int j = 0; j < 72; j++){
    float v = sc[j][tid];
    float e = expf((j < 62 ? bg : cg) * v - mx);
    sum += e;
    sc[j][tid] = e * v;
  }
  float inv = 1.f / sum;
#pragma unroll
  for (int j = 0; j < 72; j++)
    outb[(long)b*36864 + j*512 + o] = f2bf(sc[j][tid] * inv);
}

// 8) reduce 16 split-K partials -> h1 (1024 x 512) fp32, float4
__global__ __launch_bounds__(256) void k_reduce(
    const float4* __restrict__ P, float4* __restrict__ h1){
  int idx = blockIdx.x*256 + threadIdx.x;   // 0 .. 131071
  float4 v = make_float4(0.f,0.f,0.f,0.f);
#pragma unroll
  for (int s = 0; s < 16; s++){
    float4 p = P[(long)s*131072 + idx];
    v.x += p.x; v.y += p.y; v.z += p.z; v.w += p.w;
  }
  h1[idx] = v;
}

// 9) batch-norm stats (ddof=0), 8 columns per block
template<int N>
__global__ __launch_bounds__(256) void k_stats(
    const float* __restrict__ h, float* __restrict__ mu, float* __restrict__ rs){
  __shared__ float ls[256], ls2[256];
  int j0 = blockIdx.x * 8;
  int jj = threadIdx.x & 7, bg = threadIdx.x >> 3;
  float s = 0.f, s2 = 0.f;
#pragma unroll 4
  for (int it = 0; it < 32; it++){
    float v = h[(long)(it*32 + bg)*N + j0 + jj];
    s += v; s2 = fmaf(v, v, s2);
  }
  ls[threadIdx.x] = s; ls2[threadIdx.x] = s2;
  __syncthreads();
  if (threadIdx.x < 8){
    float a = ls[threadIdx.x], a2 = ls2[threadIdx.x];
    for (int g = 1; g < 32; g++){ a += ls[g*8 + threadIdx.x]; a2 += ls2[g*8 + threadIdx.x]; }
    float m = a * (1.f/1024.f);
    float var = a2 * (1.f/1024.f) - m*m;
    mu[j0 + threadIdx.x] = m;
    rs[j0 + threadIdx.x] = rsqrtf(var + 1e-5f);
  }
}

// 9b) H1B = bf16(gelu(bn1(h1)))   (1024x512)
__global__ __launch_bounds__(256) void k_bngelu(
    const float* __restrict__ h1, const float* __restrict__ mu,
    const float* __restrict__ rs, const float* __restrict__ gam,
    const float* __restrict__ bet, unsigned short* __restrict__ h1b){
  int base = (blockIdx.x*256 + threadIdx.x) * 4;
  int j = base & 511;
  float4 v = *(const float4*)(h1 + base);
  ushort4 u;
  u.x = f2bf(gelu_exact((v.x - mu[j+0])*rs[j+0]*gam[j+0] + bet[j+0]));
  u.y = f2bf(gelu_exact((v.y - mu[j+1])*rs[j+1]*gam[j+1] + bet[j+1]));
  u.z = f2bf(gelu_exact((v.z - mu[j+2])*rs[j+2]*gam[j+2] + bet[j+2]));
  u.w = f2bf(gelu_exact((v.w - mu[j+3])*rs[j+3]*gam[j+3] + bet[j+3]));
  *(ushort4*)(h1b + base) = u;
}

// 11) final: bn2+gelu, @ hc_w3 + hc_b3, softmax over 4 -> d_out
__global__ __launch_bounds__(256) void k_final(
    const float* __restrict__ h2, const float* __restrict__ mu,
    const float* __restrict__ rs, const float* __restrict__ gam,
    const float* __restrict__ bet, const float* __restrict__ w3,
    const float* __restrict__ b3, float* __restrict__ outp){
  int b = blockIdx.x, tid = threadIdx.x;
  float v = h2[(long)b*256 + tid];
  v = (v - mu[tid]) * rs[tid] * gam[tid] + bet[tid];
  v = gelu_exact(v);
  float4 w = ((const float4*)w3)[tid];
  float p0 = v*w.x, p1 = v*w.y, p2 = v*w.z, p3 = v*w.w;
#pragma unroll
  for (int o = 32; o > 0; o >>= 1){
    p0 += __shfl_down(p0, o);
    p1 += __shfl_down(p1, o);
    p2 += __shfl_down(p2, o);
    p3 += __shfl_down(p3, o);
  }
  __shared__ float red[4][4];
  int wv = tid >> 6;
  if ((tid & 63) == 0){ red[wv][0]=p0; red[wv][1]=p1; red[wv][2]=p2; red[wv][3]=p3; }
  __syncthreads();
  if (tid == 0){
    float l[4];
#pragma unroll
    for (int c = 0; c < 4; c++)
      l[c] = red[0][c]+red[1][c]+red[2][c]+red[3][c] + b3[c];
    float m = fmaxf(fmaxf(l[0], l[1]), fmaxf(l[2], l[3]));
    float e[4]; float sum = 0.f;
#pragma unroll
    for (int c = 0; c < 4; c++){ e[c] = expf(l[c]-m); sum += e[c]; }
    float inv = 1.f / sum;
#pragma unroll
    for (int c = 0; c < 4; c++) outp[(long)b*4 + c] = e[c]*inv;
  }
}

// ---------------------------------------------------------------------------
// Workspace layout (byte offsets), peak ~248 MB (same as round 4/5).
// ---------------------------------------------------------------------------
extern "C" void kernel_launch(void* const* d_in, const int* in_sizes, int n_in,
                              void* d_out, int out_size, void* d_ws, size_t ws_size,
                              hipStream_t stream){
  (void)n_in; (void)out_size; (void)ws_size;
  bool dictOrder = (in_sizes[9] == 2560);
  const float* x     = (const float*)d_in[0];
  const float* tfe_w = (const float*)d_in[1];
  const float* tfe_b = (const float*)d_in[2];
  const float* ch1w  = (const float*)d_in[3];
  const float* Amat  = (const float*)d_in[4];
  const float* ch2w  = (const float*)d_in[5];
  const float* A1mat = (const float*)d_in[6];
  const float* bgate = (const float*)d_in[7];
  const float* cgate = (const float*)d_in[8];
  const float* regb  = (const float*)d_in[dictOrder ? 9 : 19];
  int o = dictOrder ? 0 : 10;
  const float* hc_w1 = (const float*)d_in[10+o];
  const float* bn1g  = (const float*)d_in[12+o];
  const float* bn1b  = (const float*)d_in[13+o];
  const float* hc_w2 = (const float*)d_in[14+o];
  const float* bn2g  = (const float*)d_in[16+o];
  const float* bn2b  = (const float*)d_in[17+o];
  const float* hc_w3 = (const float*)d_in[18+o];
  const float* hc_b3 = (const float*)d_in[19+o];
  Ptr10 rws;
  for (int i = 0; i < 10; i++) rws.p[i] = (const float*)d_in[(dictOrder ? 20 : 9) + i];

  char* Wb = (char*)d_ws;
  unsigned short* ARb   = (unsigned short*)(Wb + 0);
  unsigned short* XCAT  = (unsigned short*)(Wb + 16252928);
  unsigned short* RWT   = (unsigned short*)(Wb + 65011712);
  float*          G2IN  = (float*)(Wb + 69074944);
  unsigned short* X2CAT = (unsigned short*)(Wb + 79560704);
  unsigned short* W1T   = (unsigned short*)(Wb + 95289344);
  unsigned short* WC1T  = (unsigned short*)(Wb + 133038080);
  unsigned short* WC2T  = (unsigned short*)(Wb + 133431296);
  unsigned short* G1    = (unsigned short*)(Wb + 134217728);
  unsigned short* G2    = (unsigned short*)(Wb + 199229440);
  unsigned short* OUTB  = (unsigned short*)(Wb + 0);
  float*          P     = (float*)(Wb + 209715200);
  float*          H1    = (float*)(Wb + 243269632);
  float*          H2    = (float*)(Wb + 245366784);
  float*          MU1   = (float*)(Wb + 246415360);
  float*          RS1   = MU1 + 512;
  float*          MU2   = MU1 + 1024;
  float*          RS2   = MU1 + 1280;
  float*          AT    = (float*)(Wb + 246423552);
  float*          A2T   = (float*)(Wb + 246439040);
  unsigned short* W2T   = (unsigned short*)(Wb + 246454528);
  unsigned short* H1B   = (unsigned short*)(Wb + 246716928);

  // prep: all weight transforms in one launch
  k_prep_all<<<7406, 256, 0, stream>>>(hc_w1, W1T, hc_w2, W2T, ch1w, WC1T,
                                       ch2w, WC2T, rws, RWT, Amat, AT, A2T);
  // g (massively parallel, HBM-bound) then spread hops
  k_g<<<1024*62, 128, 0, stream>>>(x, tfe_w, tfe_b, ARb, XCAT);
  k_spread2<<<1024, 256, 0, stream>>>(ARb, AT, A2T, XCAT);
  k_mfma_region<<<dim3(8,2,10), 256, 0, stream>>>(ARb, RWT, regb, G2IN);
  k_x2cat<<<1024, 256, 0, stream>>>(G2IN, A1mat, X2CAT);
  // cheby2: (10240 x 768) @ (768 x 512), swizzled 320 blocks (mc=40)
  k_mfma<true><<<320, 256, 0, stream>>>(X2CAT, 768, WC2T, 768, (void*)G2, 512, 768, 0, 40);
  // cheby1: (63488 x 384) @ (384 x 512), swizzled 1984 blocks (mc=248)
  k_mfma<true><<<1984, 256, 0, stream>>>(XCAT, 384, WC1T, 384, (void*)G1, 512, 384, 0, 248);
  k_softcat<<<dim3(1024,4), 128, 0, stream>>>(G1, G2, bgate, cgate, OUTB);
  // h1: (1024 x 36864) @ (36864 x 512), split-K=16, swizzled 512 blocks (mc=4)
  k_mfma<false><<<512, 256, 0, stream>>>(OUTB, 36864, W1T, 36864, (void*)P, 512, 2304, 524288, 4);
  k_reduce<<<512, 256, 0, stream>>>((const float4*)P, (float4*)H1);
  k_stats<512><<<64, 256, 0, stream>>>(H1, MU1, RS1);
  k_bngelu<<<512, 256, 0, stream>>>(H1, MU1, RS1, bn1g, bn1b, H1B);
  // h2: (1024 x 512) @ (512 x 256), plain grid
  k_mfma<false><<<dim3(8,2,1), 256, 0, stream>>>(H1B, 512, W2T, 512, (void*)H2, 256, 512, 0, 0);
  k_stats<256><<<32, 256, 0, stream>>>(H2, MU2, RS2);
  k_final<<<1024, 256, 0, stream>>>(H2, MU2, RS2, bn2g, bn2b, hc_w3, hc_b3, (float*)d_out);
}